// Round 2
// baseline (488.576 us; speedup 1.0000x reference)
//
#include <hip/hip_runtime.h>

#define T_SEQ 2048
#define DM 1024
#define NH 16
#define DKH 64
#define NB 2
#define M_ROWS (NB * T_SEQ)  // 4096

using bf16x8 = __attribute__((ext_vector_type(8))) __bf16;
using f32x4  = __attribute__((ext_vector_type(4))) float;

__device__ __forceinline__ short f2bf(float f) {
  unsigned u = __builtin_bit_cast(unsigned, f);
  u += 0x7fffu + ((u >> 16) & 1u);
  return (short)(u >> 16);
}

// ---------------- projection GEMM: Y = X @ W + bias ----------------
// X: [M][1024] (fp32 if XF32 else bf16), W: [1024][1024] fp32, bias fp32.
// HEADSPLIT: Y as [b][h][t][dk] bf16; else flat [m][n] (fp32 if YF32 else bf16).
template <bool XF32, bool HEADSPLIT, bool YF32>
__global__ __launch_bounds__(256) void proj_kernel(
    const void* __restrict__ Xv, const float* __restrict__ W,
    const float* __restrict__ bias, void* __restrict__ Yv) {
  __shared__ short As[64][40];  // [m][k] bf16, pad 32->40
  __shared__ short Bs[64][40];  // [n][k] bf16 (W transposed on load)
  const int m0 = blockIdx.x * 64, n0 = blockIdx.y * 64;
  const int tid = threadIdx.x;
  const int w = tid >> 6, lane = tid & 63, quad = lane >> 4, lm = lane & 15;
  f32x4 acc[4] = {};
  const int ar = tid >> 2, ac = (tid & 3) * 8;  // A: 64 rows x 4x8 k-chunks
  const int bk = tid >> 3, bn = (tid & 7) * 8;  // W: 32 k-rows x 8x8 n-chunks

  for (int k0 = 0; k0 < DM; k0 += 32) {
    __syncthreads();
    if (XF32) {
      const float* X = (const float*)Xv;
      float4 a0 = *(const float4*)(X + (size_t)(m0 + ar) * DM + k0 + ac);
      float4 a1 = *(const float4*)(X + (size_t)(m0 + ar) * DM + k0 + ac + 4);
      short t[8] = {f2bf(a0.x), f2bf(a0.y), f2bf(a0.z), f2bf(a0.w),
                    f2bf(a1.x), f2bf(a1.y), f2bf(a1.z), f2bf(a1.w)};
      *(int4*)&As[ar][ac] = *(const int4*)t;
    } else {
      const short* X = (const short*)Xv;
      *(int4*)&As[ar][ac] = *(const int4*)(X + (size_t)(m0 + ar) * DM + k0 + ac);
    }
    float4 b0 = *(const float4*)(W + (size_t)(k0 + bk) * DM + n0 + bn);
    float4 b1 = *(const float4*)(W + (size_t)(k0 + bk) * DM + n0 + bn + 4);
    float bb[8] = {b0.x, b0.y, b0.z, b0.w, b1.x, b1.y, b1.z, b1.w};
#pragma unroll
    for (int j = 0; j < 8; ++j) Bs[bn + j][bk] = f2bf(bb[j]);
    __syncthreads();
    bf16x8 af = *(const bf16x8*)&As[w * 16 + lm][quad * 8];
#pragma unroll
    for (int nt = 0; nt < 4; ++nt) {
      bf16x8 bfg = *(const bf16x8*)&Bs[nt * 16 + lm][quad * 8];
      acc[nt] = __builtin_amdgcn_mfma_f32_16x16x32_bf16(af, bfg, acc[nt], 0, 0, 0);
    }
  }
#pragma unroll
  for (int nt = 0; nt < 4; ++nt) {
    int n = n0 + nt * 16 + lm;
    float bv = bias[n];
#pragma unroll
    for (int r = 0; r < 4; ++r) {
      int m = m0 + w * 16 + quad * 4 + r;  // C/D layout: row=quad*4+reg, col=lm
      float yv = acc[nt][r] + bv;
      if (HEADSPLIT) {
        int b = m >> 11, t = m & (T_SEQ - 1), h = n >> 6, dk = n & 63;
        ((short*)Yv)[((size_t)(b * NH + h) * T_SEQ + t) * DKH + dk] = f2bf(yv);
      } else if (YF32) {
        ((float*)Yv)[(size_t)m * DM + n] = yv;
      } else {
        ((short*)Yv)[(size_t)m * DM + n] = f2bf(yv);
      }
    }
  }
}

// ---------------- flash attention ----------------
// Qh/Kh/Vh: [32][2048][64] bf16 (head-split).  Aout: [4096][1024] bf16 (head-merged).
__global__ __launch_bounds__(256) void attn_kernel(
    const short* __restrict__ Qh, const short* __restrict__ Kh,
    const short* __restrict__ Vh, const int* __restrict__ mask,
    short* __restrict__ Aout) {
  __shared__ short Ks[64][72];      // [key][dk], pad 64->72
  __shared__ short Vt[64][72];      // [dk][key] transposed
  __shared__ short Pb[4][16][72];   // per-wave P transpose buffer
  const int qt = blockIdx.x, bh = blockIdx.y;
  const int b = bh >> 4, h = bh & (NH - 1);
  const int tid = threadIdx.x;
  const int w = tid >> 6, lane = tid & 63, quad = lane >> 4, lm = lane & 15;
  const size_t base = (size_t)bh * T_SEQ * DKH;
  const int q0 = qt * 64 + w * 16;

  // persistent Q fragments (A-operand layout: m=lm, k=quad*8+j)
  bf16x8 qf0 = *(const bf16x8*)(Qh + base + (size_t)(q0 + lm) * DKH + quad * 8);
  bf16x8 qf1 = *(const bf16x8*)(Qh + base + (size_t)(q0 + lm) * DKH + 32 + quad * 8);

  f32x4 o[4] = {};
  float mrow[4], lrow[4];
#pragma unroll
  for (int r = 0; r < 4; ++r) { mrow[r] = -1e30f; lrow[r] = 0.f; }
  const int* mp = mask + b * T_SEQ;

  for (int kt = 0; kt < T_SEQ / 64; ++kt) {
    const int key0 = kt * 64;
    __syncthreads();
    // stage K tile [64][64] and V tile transposed [dk][key]
#pragma unroll
    for (int c = 0; c < 2; ++c) {
      int cid = tid + c * 256;              // 0..511
      int key = cid >> 3, d8 = (cid & 7) * 8;
      int4 kv = *(const int4*)(Kh + base + (size_t)(key0 + key) * DKH + d8);
      *(int4*)&Ks[key][d8] = kv;
      int4 vv = *(const int4*)(Vh + base + (size_t)(key0 + key) * DKH + d8);
      const short* vs = (const short*)&vv;
#pragma unroll
      for (int j = 0; j < 8; ++j) Vt[d8 + j][key] = vs[j];
    }
    __syncthreads();

    // S = Q K^T (per wave: 16 q x 64 keys), scale + mask
    float p[4][4];
    float mx[4] = {-1e30f, -1e30f, -1e30f, -1e30f};
#pragma unroll
    for (int nt = 0; nt < 4; ++nt) {
      f32x4 s = {};
      bf16x8 kf0 = *(const bf16x8*)&Ks[nt * 16 + lm][quad * 8];
      bf16x8 kf1 = *(const bf16x8*)&Ks[nt * 16 + lm][32 + quad * 8];
      s = __builtin_amdgcn_mfma_f32_16x16x32_bf16(qf0, kf0, s, 0, 0, 0);
      s = __builtin_amdgcn_mfma_f32_16x16x32_bf16(qf1, kf1, s, 0, 0, 0);
      int key = key0 + nt * 16 + lm;
      bool valid = mp[key] != 0;
#pragma unroll
      for (int r = 0; r < 4; ++r) {
        float sv = valid ? s[r] * 0.125f : -1e30f;
        p[nt][r] = sv;
        mx[r] = fmaxf(mx[r], sv);
      }
    }
    // row-max over the 16 lanes holding this row (same quad)
#pragma unroll
    for (int off = 1; off < 16; off <<= 1)
#pragma unroll
      for (int r = 0; r < 4; ++r) mx[r] = fmaxf(mx[r], __shfl_xor(mx[r], off, 64));

    float alpha[4], rs[4] = {0, 0, 0, 0};
#pragma unroll
    for (int r = 0; r < 4; ++r) {
      float mnew = fmaxf(mrow[r], mx[r]);
      alpha[r] = __expf(mrow[r] - mnew);
      mrow[r] = mnew;
#pragma unroll
      for (int nt = 0; nt < 4; ++nt) {
        float pv = __expf(p[nt][r] - mnew);
        p[nt][r] = pv;
        rs[r] += pv;
      }
    }
#pragma unroll
    for (int off = 1; off < 16; off <<= 1)
#pragma unroll
      for (int r = 0; r < 4; ++r) rs[r] += __shfl_xor(rs[r], off, 64);

#pragma unroll
    for (int r = 0; r < 4; ++r) {
      lrow[r] = lrow[r] * alpha[r] + rs[r];
#pragma unroll
      for (int nt = 0; nt < 4; ++nt) {
        o[nt][r] *= alpha[r];
        Pb[w][quad * 4 + r][nt * 16 + lm] = f2bf(p[nt][r]);  // C-layout -> [q][key]
      }
    }
    __syncthreads();  // make Pb visible (and keep waves aligned)

    // O += P V   (P as A-operand from Pb, V^T as B-operand)
    bf16x8 pf0 = *(const bf16x8*)&Pb[w][lm][quad * 8];
    bf16x8 pf1 = *(const bf16x8*)&Pb[w][lm][32 + quad * 8];
#pragma unroll
    for (int nt = 0; nt < 4; ++nt) {
      bf16x8 vf0 = *(const bf16x8*)&Vt[nt * 16 + lm][quad * 8];
      bf16x8 vf1 = *(const bf16x8*)&Vt[nt * 16 + lm][32 + quad * 8];
      o[nt] = __builtin_amdgcn_mfma_f32_16x16x32_bf16(pf0, vf0, o[nt], 0, 0, 0);
      o[nt] = __builtin_amdgcn_mfma_f32_16x16x32_bf16(pf1, vf1, o[nt], 0, 0, 0);
    }
  }
  // epilogue: O / l -> head-merged [m][1024] bf16
#pragma unroll
  for (int nt = 0; nt < 4; ++nt)
#pragma unroll
    for (int r = 0; r < 4; ++r) {
      float v = o[nt][r] / lrow[r];
      int m = b * T_SEQ + qt * 64 + w * 16 + quad * 4 + r;
      int n = h * DKH + nt * 16 + lm;
      Aout[(size_t)m * DM + n] = f2bf(v);
    }
}

extern "C" void kernel_launch(void* const* d_in, const int* in_sizes, int n_in,
                              void* d_out, int out_size, void* d_ws, size_t ws_size,
                              hipStream_t stream) {
  const float* q  = (const float*)d_in[0];
  const float* k  = (const float*)d_in[1];
  const float* v  = (const float*)d_in[2];
  const int*   mk = (const int*)d_in[3];
  const float* Wq = (const float*)d_in[4];
  const float* bq = (const float*)d_in[5];
  const float* Wk = (const float*)d_in[6];
  const float* bk = (const float*)d_in[7];
  const float* Wv = (const float*)d_in[8];
  const float* bv = (const float*)d_in[9];
  const float* Wo = (const float*)d_in[10];
  const float* bo = (const float*)d_in[11];

  short* Qh = (short*)d_ws;
  short* Kh = Qh + (size_t)NB * NH * T_SEQ * DKH;  // +4M elems (8 MiB each)
  short* Vh = Kh + (size_t)NB * NH * T_SEQ * DKH;
  short* Ao = Vh + (size_t)NB * NH * T_SEQ * DKH;  // [4096][1024] bf16

  dim3 pb(256);
  dim3 pg(M_ROWS / 64, DM / 64);
  proj_kernel<true, true, false><<<pg, pb, 0, stream>>>(q, Wq, bq, Qh);
  proj_kernel<true, true, false><<<pg, pb, 0, stream>>>(k, Wk, bk, Kh);
  proj_kernel<true, true, false><<<pg, pb, 0, stream>>>(v, Wv, bv, Vh);
  attn_kernel<<<dim3(T_SEQ / 64, NB * NH), pb, 0, stream>>>(Qh, Kh, Vh, mk, Ao);
  proj_kernel<false, false, true><<<pg, pb, 0, stream>>>(Ao, Wo, bo, (float*)d_out);
}

// Round 4
// 448.138 us; speedup vs baseline: 1.0902x; 1.0902x over previous
//
#include <hip/hip_runtime.h>

#define T_SEQ 2048
#define DM 1024
#define NH 16
#define DKH 64
#define NB 2
#define M_ROWS (NB * T_SEQ)  // 4096

using bf16x8 = __attribute__((ext_vector_type(8))) __bf16;
using f32x4  = __attribute__((ext_vector_type(4))) float;

__device__ __forceinline__ short f2bf(float f) {
  unsigned u = __builtin_bit_cast(unsigned, f);
  u += 0x7fffu + ((u >> 16) & 1u);
  return (short)(u >> 16);
}

#define GLD16(g, l)                                                            \
  __builtin_amdgcn_global_load_lds(                                            \
      (const __attribute__((address_space(1))) void*)(g),                      \
      (__attribute__((address_space(3))) void*)(l), 16, 0, 0)

// ---------- prep: fp32 -> bf16 convert of q,k,v ----------
__global__ __launch_bounds__(256) void prep_x(
    const float* __restrict__ q, const float* __restrict__ k,
    const float* __restrict__ v, short* __restrict__ dst) {
  const float* s = blockIdx.z == 0 ? q : (blockIdx.z == 1 ? k : v);
  short* d = dst + (size_t)blockIdx.z * (M_ROWS * DM);
  const int n4 = M_ROWS * DM / 4;
  for (int i = blockIdx.x * 256 + threadIdx.x; i < n4; i += gridDim.x * 256) {
    float4 f = *(const float4*)(s + i * 4);
    short4 o = {f2bf(f.x), f2bf(f.y), f2bf(f.z), f2bf(f.w)};
    *(short4*)(d + i * 4) = o;
  }
}

// ---------- prep: W [k][n] fp32 -> Wt [n][k] bf16 (4 matrices) ----------
__global__ __launch_bounds__(256) void prep_w(
    const float* __restrict__ w0, const float* __restrict__ w1,
    const float* __restrict__ w2, const float* __restrict__ w3,
    short* __restrict__ dst) {
  __shared__ short T[64][72];
  const float* W = blockIdx.z == 0 ? w0 : blockIdx.z == 1 ? w1
                   : blockIdx.z == 2 ? w2 : w3;
  short* D = dst + (size_t)blockIdx.z * (DM * DM);
  const int k0 = blockIdx.x * 64, n0 = blockIdx.y * 64;
  const int r = threadIdx.x >> 2, cs = (threadIdx.x & 3) * 16;
#pragma unroll
  for (int j = 0; j < 4; ++j) {
    float4 f = *(const float4*)(W + (size_t)(k0 + r) * DM + n0 + cs + j * 4);
    short4 o = {f2bf(f.x), f2bf(f.y), f2bf(f.z), f2bf(f.w)};
    *(short4*)&T[r][cs + j * 4] = o;
  }
  __syncthreads();
  short tmp[16];
#pragma unroll
  for (int i = 0; i < 16; ++i) tmp[i] = T[cs + i][r];
  *(int4*)(D + (size_t)(n0 + r) * DM + k0 + cs) = *(const int4*)&tmp[0];
  *(int4*)(D + (size_t)(n0 + r) * DM + k0 + cs + 8) = *(const int4*)&tmp[8];
}

// ---------- GEMM: Y = A(bf16 [M][K]) @ Bt(bf16 [N][K])^T + bias ----------
// 128x128 tile, BK=32, global_load_lds(16B), interleaved LDS layout:
// offset(shorts)(x, kseg) = (x>>4)*512 + kseg*128 + (x&15)*8
// MODE 0: z in {0,1,2} selects A/Bt/bias AND dst region z*XE; Y headsplit bf16
//         (z<2: [b][h][t][dk], z==2: [b][h][dk][t] i.e. V transposed).
// MODE 1: flat fp32 out.
template <int MODE>
__global__ __launch_bounds__(256) void gemm_bt(
    const short* __restrict__ A_, const short* __restrict__ Bt_,
    const float* __restrict__ b0, const float* __restrict__ b1,
    const float* __restrict__ b2, short* __restrict__ Y,
    float* __restrict__ Yf) {
  __shared__ short As[4096];
  __shared__ short Bs[4096];
  const int z = (MODE == 0) ? blockIdx.z : 0;
  const short* A = A_ + (size_t)z * (M_ROWS * DM);
  const short* Bt = Bt_ + (size_t)z * (DM * DM);
  short* Yz = (MODE == 0) ? (Y + (size_t)z * ((size_t)M_ROWS * DM)) : Y;  // FIX
  const float* bias = (MODE == 0) ? (z == 0 ? b0 : (z == 1 ? b1 : b2)) : b0;
  const int m0 = blockIdx.x * 128, n0 = blockIdx.y * 128;
  const int tid = threadIdx.x, w = tid >> 6, lane = tid & 63;
  const int quad = lane >> 4, lm = lane & 15, wm = w & 1, wn = w >> 1;

  // staging: wave w covers rows w*32 + c*16 + (lane&15), kseg = lane>>4
  const short* Ag = A + (size_t)(m0 + w * 32 + lm) * DM + quad * 8;
  const short* Bg = Bt + (size_t)(n0 + w * 32 + lm) * DM + quad * 8;
  short* Ad0 = &As[w * 1024];
  short* Ad1 = &As[w * 1024 + 512];
  short* Bd0 = &Bs[w * 1024];
  short* Bd1 = &Bs[w * 1024 + 512];

  f32x4 acc[4][4];
#pragma unroll
  for (int i = 0; i < 4; ++i)
#pragma unroll
    for (int j = 0; j < 4; ++j) acc[i][j] = (f32x4){0.f, 0.f, 0.f, 0.f};

  for (int k0 = 0; k0 < DM; k0 += 32) {
    __syncthreads();
    GLD16(Ag + k0, Ad0);
    GLD16(Ag + 16 * DM + k0, Ad1);
    GLD16(Bg + k0, Bd0);
    GLD16(Bg + 16 * DM + k0, Bd1);
    __syncthreads();
    bf16x8 af[4], bfr[4];
#pragma unroll
    for (int i = 0; i < 4; ++i) {
      af[i] = *(const bf16x8*)&As[(wm * 4 + i) * 512 + quad * 128 + lm * 8];
      bfr[i] = *(const bf16x8*)&Bs[(wn * 4 + i) * 512 + quad * 128 + lm * 8];
    }
#pragma unroll
    for (int mi = 0; mi < 4; ++mi)
#pragma unroll
      for (int ni = 0; ni < 4; ++ni)
        acc[mi][ni] = __builtin_amdgcn_mfma_f32_16x16x32_bf16(
            af[mi], bfr[ni], acc[mi][ni], 0, 0, 0);
  }

#pragma unroll
  for (int ni = 0; ni < 4; ++ni) {
    const int n = n0 + wn * 64 + ni * 16 + lm;
    const float bv = bias[n];
#pragma unroll
    for (int mi = 0; mi < 4; ++mi)
#pragma unroll
      for (int r = 0; r < 4; ++r) {
        const int m = m0 + wm * 64 + mi * 16 + quad * 4 + r;
        const float val = acc[mi][ni][r] + bv;
        if (MODE == 0) {
          const int b = m >> 11, t = m & (T_SEQ - 1), h = n >> 6, dk = n & 63;
          if (z == 2)
            Yz[(((size_t)(b * NH + h) * DKH + dk) << 11) + t] = f2bf(val);
          else
            Yz[(((size_t)(b * NH + h) << 11) + t) * DKH + dk] = f2bf(val);
        } else {
          Yf[(size_t)m * DM + n] = val;
        }
      }
  }
}

// ---------- flash attention, barrier-free ----------
// Qh/Kh: [bh][t][dk] bf16, Vt: [bh][dk][t] bf16, Ao: [4096][1024] bf16.
// Per wave: 16 q rows. S^T = K.Q^T (C layout: row=key, col=q=lm) so softmax
// state is one scalar per lane. P -> per-wave LDS [q][key] -> B-frag for
// O^T = V^T.P^T. No __syncthreads anywhere.
__global__ __launch_bounds__(256) void attn_kernel(
    const short* __restrict__ Qh, const short* __restrict__ Kh,
    const short* __restrict__ Vt, const int* __restrict__ mask,
    short* __restrict__ Ao) {
  __shared__ short Pq[4][16][72];
  const int qt = blockIdx.x, bh = blockIdx.y;
  const int b = bh >> 4, h = bh & (NH - 1);
  const int tid = threadIdx.x, w = tid >> 6, lane = tid & 63;
  const int quad = lane >> 4, lm = lane & 15;
  const size_t base = (size_t)bh * T_SEQ * DKH;
  const int* mp = mask + b * T_SEQ;
  const int q0 = qt * 64 + w * 16;

  const bf16x8 qb0 = *(const bf16x8*)(Qh + base + (size_t)(q0 + lm) * DKH + quad * 8);
  const bf16x8 qb1 = *(const bf16x8*)(Qh + base + (size_t)(q0 + lm) * DKH + 32 + quad * 8);

  f32x4 ot[4];
#pragma unroll
  for (int i = 0; i < 4; ++i) ot[i] = (f32x4){0.f, 0.f, 0.f, 0.f};
  float m_i = -1e30f, l_i = 0.f;

  for (int key0 = 0; key0 < T_SEQ; key0 += 64) {
    float sc[4][4];
    float smax = -1e30f;
#pragma unroll
    for (int nt = 0; nt < 4; ++nt) {
      const short* kp = Kh + base + (size_t)(key0 + nt * 16 + lm) * DKH;
      bf16x8 ka0 = *(const bf16x8*)(kp + quad * 8);
      bf16x8 ka1 = *(const bf16x8*)(kp + 32 + quad * 8);
      f32x4 s = (f32x4){0.f, 0.f, 0.f, 0.f};
      s = __builtin_amdgcn_mfma_f32_16x16x32_bf16(ka0, qb0, s, 0, 0, 0);
      s = __builtin_amdgcn_mfma_f32_16x16x32_bf16(ka1, qb1, s, 0, 0, 0);
#pragma unroll
      for (int r = 0; r < 4; ++r) {
        float sv = s[r] * 0.125f;
        sc[nt][r] = sv;
        smax = fmaxf(smax, sv);
      }
    }
    smax = fmaxf(smax, __shfl_xor(smax, 16, 64));
    smax = fmaxf(smax, __shfl_xor(smax, 32, 64));
    const float mnew = fmaxf(m_i, smax);
    const float alpha = __expf(m_i - mnew);
    m_i = mnew;
    float rsum = 0.f;
#pragma unroll
    for (int nt = 0; nt < 4; ++nt) {
      int4 mk = *(const int4*)(mp + key0 + nt * 16 + quad * 4);
      float p0 = mk.x ? __expf(sc[nt][0] - mnew) : 0.f;
      float p1 = mk.y ? __expf(sc[nt][1] - mnew) : 0.f;
      float p2 = mk.z ? __expf(sc[nt][2] - mnew) : 0.f;
      float p3 = mk.w ? __expf(sc[nt][3] - mnew) : 0.f;
      rsum += (p0 + p1) + (p2 + p3);
      short4 s4 = {f2bf(p0), f2bf(p1), f2bf(p2), f2bf(p3)};
      *(short4*)&Pq[w][lm][nt * 16 + quad * 4] = s4;  // P[q][key]
    }
    rsum += __shfl_xor(rsum, 16, 64);
    rsum += __shfl_xor(rsum, 32, 64);
    l_i = l_i * alpha + rsum;
#pragma unroll
    for (int nt = 0; nt < 4; ++nt)
#pragma unroll
      for (int r = 0; r < 4; ++r) ot[nt][r] *= alpha;

    const bf16x8 pb0 = *(const bf16x8*)&Pq[w][lm][quad * 8];
    const bf16x8 pb1 = *(const bf16x8*)&Pq[w][lm][32 + quad * 8];
#pragma unroll
    for (int nt = 0; nt < 4; ++nt) {
      const short* vp = Vt + base + (size_t)(nt * 16 + lm) * T_SEQ + key0;
      bf16x8 va0 = *(const bf16x8*)(vp + quad * 8);
      bf16x8 va1 = *(const bf16x8*)(vp + 32 + quad * 8);
      ot[nt] = __builtin_amdgcn_mfma_f32_16x16x32_bf16(va0, pb0, ot[nt], 0, 0, 0);
      ot[nt] = __builtin_amdgcn_mfma_f32_16x16x32_bf16(va1, pb1, ot[nt], 0, 0, 0);
    }
  }
  const float inv = 1.f / l_i;
  const size_t row = (size_t)(b * T_SEQ + qt * 64 + w * 16 + lm) * DM + h * DKH;
#pragma unroll
  for (int nt = 0; nt < 4; ++nt) {
    short4 o4 = {f2bf(ot[nt][0] * inv), f2bf(ot[nt][1] * inv),
                 f2bf(ot[nt][2] * inv), f2bf(ot[nt][3] * inv)};
    *(short4*)(Ao + row + nt * 16 + quad * 4) = o4;
  }
}

extern "C" void kernel_launch(void* const* d_in, const int* in_sizes, int n_in,
                              void* d_out, int out_size, void* d_ws, size_t ws_size,
                              hipStream_t stream) {
  const float* q = (const float*)d_in[0];
  const float* k = (const float*)d_in[1];
  const float* v = (const float*)d_in[2];
  const int* mk = (const int*)d_in[3];
  const float* Wq = (const float*)d_in[4];
  const float* bq = (const float*)d_in[5];
  const float* Wk = (const float*)d_in[6];
  const float* bk = (const float*)d_in[7];
  const float* Wv = (const float*)d_in[8];
  const float* bv = (const float*)d_in[9];
  const float* Wo = (const float*)d_in[10];
  const float* bo = (const float*)d_in[11];

  const size_t XE = (size_t)M_ROWS * DM;  // 4194304
  const size_t WE = (size_t)DM * DM;      // 1048576
  short* xb = (short*)d_ws;               // 3*XE  (dead after QKV gemm)
  short* Wt = xb + 3 * XE;                // 4*WE
  short* Qh = Wt + 4 * WE;                // 3*XE: Qh, Kh, Vt contiguous
  short* Ao = xb;                         // alias: xb region reused for Ao

  prep_x<<<dim3(1024, 1, 3), 256, 0, stream>>>(q, k, v, xb);
  prep_w<<<dim3(16, 16, 4), 256, 0, stream>>>(Wq, Wk, Wv, Wo, Wt);
  // QKV: z selects (x, W, bias, dst z*XE); V written transposed [b][h][dk][t]
  gemm_bt<0><<<dim3(M_ROWS / 128, DM / 128, 3), 256, 0, stream>>>(
      xb, Wt, bq, bk, bv, Qh, nullptr);
  attn_kernel<<<dim3(T_SEQ / 64, NB * NH), 256, 0, stream>>>(
      Qh, Qh + XE, Qh + 2 * XE, mk, Ao);
  gemm_bt<1><<<dim3(M_ROWS / 128, DM / 128, 1), 256, 0, stream>>>(
      Ao, Wt + 3 * WE, bo, nullptr, nullptr, nullptr, (float*)d_out);
}

// Round 5
// 307.095 us; speedup vs baseline: 1.5910x; 1.4593x over previous
//
#include <hip/hip_runtime.h>

#define T_SEQ 2048
#define DM 1024
#define NH 16
#define DKH 64
#define NB 2
#define M_ROWS (NB * T_SEQ)  // 4096

using bf16x8 = __attribute__((ext_vector_type(8))) __bf16;
using f32x4  = __attribute__((ext_vector_type(4))) float;

__device__ __forceinline__ short f2bf(float f) {
  unsigned u = __builtin_bit_cast(unsigned, f);
  u += 0x7fffu + ((u >> 16) & 1u);
  return (short)(u >> 16);
}

#define GLD16(g, l)                                                            \
  __builtin_amdgcn_global_load_lds(                                            \
      (const __attribute__((address_space(1))) void*)(g),                      \
      (__attribute__((address_space(3))) void*)(l), 16, 0, 0)

// ---------- prep: fp32 -> bf16 convert of q,k,v ----------
__global__ __launch_bounds__(256) void prep_x(
    const float* __restrict__ q, const float* __restrict__ k,
    const float* __restrict__ v, short* __restrict__ dst) {
  const float* s = blockIdx.z == 0 ? q : (blockIdx.z == 1 ? k : v);
  short* d = dst + (size_t)blockIdx.z * (M_ROWS * DM);
  const int n4 = M_ROWS * DM / 4;
  for (int i = blockIdx.x * 256 + threadIdx.x; i < n4; i += gridDim.x * 256) {
    float4 f = *(const float4*)(s + i * 4);
    short4 o = {f2bf(f.x), f2bf(f.y), f2bf(f.z), f2bf(f.w)};
    *(short4*)(d + i * 4) = o;
  }
}

// ---------- prep: W [k][n] fp32 -> Wt [n][k] bf16 (4 matrices) ----------
__global__ __launch_bounds__(256) void prep_w(
    const float* __restrict__ w0, const float* __restrict__ w1,
    const float* __restrict__ w2, const float* __restrict__ w3,
    short* __restrict__ dst) {
  __shared__ short T[64][72];
  const float* W = blockIdx.z == 0 ? w0 : blockIdx.z == 1 ? w1
                   : blockIdx.z == 2 ? w2 : w3;
  short* D = dst + (size_t)blockIdx.z * (DM * DM);
  const int k0 = blockIdx.x * 64, n0 = blockIdx.y * 64;
  const int r = threadIdx.x >> 2, cs = (threadIdx.x & 3) * 16;
#pragma unroll
  for (int j = 0; j < 4; ++j) {
    float4 f = *(const float4*)(W + (size_t)(k0 + r) * DM + n0 + cs + j * 4);
    short4 o = {f2bf(f.x), f2bf(f.y), f2bf(f.z), f2bf(f.w)};
    *(short4*)&T[r][cs + j * 4] = o;
  }
  __syncthreads();
  short tmp[16];
#pragma unroll
  for (int i = 0; i < 16; ++i) tmp[i] = T[cs + i][r];
  *(int4*)(D + (size_t)(n0 + r) * DM + k0 + cs) = *(const int4*)&tmp[0];
  *(int4*)(D + (size_t)(n0 + r) * DM + k0 + cs + 8) = *(const int4*)&tmp[8];
}

// ---------- GEMM: Y = A(bf16 [M][K]) @ Bt(bf16 [N][K])^T + bias ----------
template <int MODE>
__global__ __launch_bounds__(256) void gemm_bt(
    const short* __restrict__ A_, const short* __restrict__ Bt_,
    const float* __restrict__ b0, const float* __restrict__ b1,
    const float* __restrict__ b2, short* __restrict__ Y,
    float* __restrict__ Yf) {
  __shared__ short As[4096];
  __shared__ short Bs[4096];
  const int z = (MODE == 0) ? blockIdx.z : 0;
  const short* A = A_ + (size_t)z * (M_ROWS * DM);
  const short* Bt = Bt_ + (size_t)z * (DM * DM);
  short* Yz = (MODE == 0) ? (Y + (size_t)z * ((size_t)M_ROWS * DM)) : Y;
  const float* bias = (MODE == 0) ? (z == 0 ? b0 : (z == 1 ? b1 : b2)) : b0;
  const int m0 = blockIdx.x * 128, n0 = blockIdx.y * 128;
  const int tid = threadIdx.x, w = tid >> 6, lane = tid & 63;
  const int quad = lane >> 4, lm = lane & 15, wm = w & 1, wn = w >> 1;

  const short* Ag = A + (size_t)(m0 + w * 32 + lm) * DM + quad * 8;
  const short* Bg = Bt + (size_t)(n0 + w * 32 + lm) * DM + quad * 8;
  short* Ad0 = &As[w * 1024];
  short* Ad1 = &As[w * 1024 + 512];
  short* Bd0 = &Bs[w * 1024];
  short* Bd1 = &Bs[w * 1024 + 512];

  f32x4 acc[4][4];
#pragma unroll
  for (int i = 0; i < 4; ++i)
#pragma unroll
    for (int j = 0; j < 4; ++j) acc[i][j] = (f32x4){0.f, 0.f, 0.f, 0.f};

  for (int k0 = 0; k0 < DM; k0 += 32) {
    __syncthreads();
    GLD16(Ag + k0, Ad0);
    GLD16(Ag + 16 * DM + k0, Ad1);
    GLD16(Bg + k0, Bd0);
    GLD16(Bg + 16 * DM + k0, Bd1);
    __syncthreads();
    bf16x8 af[4], bfr[4];
#pragma unroll
    for (int i = 0; i < 4; ++i) {
      af[i] = *(const bf16x8*)&As[(wm * 4 + i) * 512 + quad * 128 + lm * 8];
      bfr[i] = *(const bf16x8*)&Bs[(wn * 4 + i) * 512 + quad * 128 + lm * 8];
    }
#pragma unroll
    for (int mi = 0; mi < 4; ++mi)
#pragma unroll
      for (int ni = 0; ni < 4; ++ni)
        acc[mi][ni] = __builtin_amdgcn_mfma_f32_16x16x32_bf16(
            af[mi], bfr[ni], acc[mi][ni], 0, 0, 0);
  }

#pragma unroll
  for (int ni = 0; ni < 4; ++ni) {
    const int n = n0 + wn * 64 + ni * 16 + lm;
    const float bv = bias[n];
#pragma unroll
    for (int mi = 0; mi < 4; ++mi)
#pragma unroll
      for (int r = 0; r < 4; ++r) {
        const int m = m0 + wm * 64 + mi * 16 + quad * 4 + r;
        const float val = acc[mi][ni][r] + bv;
        if (MODE == 0) {
          const int b = m >> 11, t = m & (T_SEQ - 1), h = n >> 6, dk = n & 63;
          if (z == 2)
            Yz[(((size_t)(b * NH + h) * DKH + dk) << 11) + t] = f2bf(val);
          else
            Yz[(((size_t)(b * NH + h) << 11) + t) * DKH + dk] = f2bf(val);
        } else {
          Yf[(size_t)m * DM + n] = val;
        }
      }
  }
}

// ---------- flash attention: LDS-staged K/V (GLD16), per-lane softmax ----------
// Qh/Kh: [bh][t][dk] bf16, Vt: [bh][dk][t] bf16, Ao: [4096][1024] bf16.
// S^T = K.Q^T (C layout: row=key, col=q=lm) -> one softmax scalar per lane.
// K tile & V^T tile cooperatively staged via global_load_lds into interleaved
// layout off(row,c8) = (row>>4)*1024 + (c8>>2)*512 + (c8&3)*128 + (row&15)*8.
// P goes through per-wave LDS (no barrier); O^T = V^T.P^T.
__global__ __launch_bounds__(256) void attn_kernel(
    const short* __restrict__ Qh, const short* __restrict__ Kh,
    const short* __restrict__ Vt, const int* __restrict__ mask,
    short* __restrict__ Ao) {
  __shared__ short Ks[4096];      // 64 keys x 64 dk
  __shared__ short Vs[4096];      // 64 dk x 64 keys
  __shared__ short Pq[4][16][72]; // per-wave P [q][key]
  const int qt = blockIdx.x, bh = blockIdx.y;
  const int b = bh >> 4, h = bh & (NH - 1);
  const int tid = threadIdx.x, w = tid >> 6, lane = tid & 63;
  const int quad = lane >> 4, lm = lane & 15;
  const size_t base = (size_t)bh * T_SEQ * DKH;
  const int* mp = mask + b * T_SEQ;
  const int q0 = qt * 64 + w * 16;

  const bf16x8 qb0 = *(const bf16x8*)(Qh + base + (size_t)(q0 + lm) * DKH + quad * 8);
  const bf16x8 qb1 = *(const bf16x8*)(Qh + base + (size_t)(q0 + lm) * DKH + 32 + quad * 8);

  // staging: wave w stages K rows [w*16+lm] (halves dk 0-31 / 32-63)
  // and V^T rows [w*16+lm] (halves key 0-31 / 32-63 of the tile)
  const short* Kg = Kh + base + (size_t)(w * 16 + lm) * DKH + quad * 8;
  const short* Vg = Vt + base + (size_t)(w * 16 + lm) * T_SEQ + quad * 8;
  short* Kd0 = &Ks[w * 1024];
  short* Kd1 = &Ks[w * 1024 + 512];
  short* Vd0 = &Vs[w * 1024];
  short* Vd1 = &Vs[w * 1024 + 512];

  f32x4 ot[4];
#pragma unroll
  for (int i = 0; i < 4; ++i) ot[i] = (f32x4){0.f, 0.f, 0.f, 0.f};
  float m_i = -1e30f, l_i = 0.f;

  for (int key0 = 0; key0 < T_SEQ; key0 += 64) {
    __syncthreads();
    GLD16(Kg + (size_t)key0 * DKH, Kd0);
    GLD16(Kg + (size_t)key0 * DKH + 32, Kd1);
    GLD16(Vg + key0, Vd0);
    GLD16(Vg + key0 + 32, Vd1);
    __syncthreads();

    float sc[4][4];
    float smax = -1e30f;
#pragma unroll
    for (int nt = 0; nt < 4; ++nt) {
      bf16x8 ka0 = *(const bf16x8*)&Ks[nt * 1024 + quad * 128 + lm * 8];
      bf16x8 ka1 = *(const bf16x8*)&Ks[nt * 1024 + 512 + quad * 128 + lm * 8];
      f32x4 s = (f32x4){0.f, 0.f, 0.f, 0.f};
      s = __builtin_amdgcn_mfma_f32_16x16x32_bf16(ka0, qb0, s, 0, 0, 0);
      s = __builtin_amdgcn_mfma_f32_16x16x32_bf16(ka1, qb1, s, 0, 0, 0);
#pragma unroll
      for (int r = 0; r < 4; ++r) {
        float sv = s[r] * 0.125f;
        sc[nt][r] = sv;
        smax = fmaxf(smax, sv);
      }
    }
    smax = fmaxf(smax, __shfl_xor(smax, 16, 64));
    smax = fmaxf(smax, __shfl_xor(smax, 32, 64));
    const float mnew = fmaxf(m_i, smax);
    const float alpha = __expf(m_i - mnew);
    m_i = mnew;
    float rsum = 0.f;
#pragma unroll
    for (int nt = 0; nt < 4; ++nt) {
      int4 mk = *(const int4*)(mp + key0 + nt * 16 + quad * 4);
      float p0 = mk.x ? __expf(sc[nt][0] - mnew) : 0.f;
      float p1 = mk.y ? __expf(sc[nt][1] - mnew) : 0.f;
      float p2 = mk.z ? __expf(sc[nt][2] - mnew) : 0.f;
      float p3 = mk.w ? __expf(sc[nt][3] - mnew) : 0.f;
      rsum += (p0 + p1) + (p2 + p3);
      short4 s4 = {f2bf(p0), f2bf(p1), f2bf(p2), f2bf(p3)};
      *(short4*)&Pq[w][lm][nt * 16 + quad * 4] = s4;  // P[q][key]
    }
    rsum += __shfl_xor(rsum, 16, 64);
    rsum += __shfl_xor(rsum, 32, 64);
    l_i = l_i * alpha + rsum;
#pragma unroll
    for (int nt = 0; nt < 4; ++nt)
#pragma unroll
      for (int r = 0; r < 4; ++r) ot[nt][r] *= alpha;

    const bf16x8 pb0 = *(const bf16x8*)&Pq[w][lm][quad * 8];
    const bf16x8 pb1 = *(const bf16x8*)&Pq[w][lm][32 + quad * 8];
#pragma unroll
    for (int nt = 0; nt < 4; ++nt) {
      bf16x8 va0 = *(const bf16x8*)&Vs[nt * 1024 + quad * 128 + lm * 8];
      bf16x8 va1 = *(const bf16x8*)&Vs[nt * 1024 + 512 + quad * 128 + lm * 8];
      ot[nt] = __builtin_amdgcn_mfma_f32_16x16x32_bf16(va0, pb0, ot[nt], 0, 0, 0);
      ot[nt] = __builtin_amdgcn_mfma_f32_16x16x32_bf16(va1, pb1, ot[nt], 0, 0, 0);
    }
  }
  const float inv = 1.f / l_i;
  const size_t row = (size_t)(b * T_SEQ + qt * 64 + w * 16 + lm) * DM + h * DKH;
#pragma unroll
  for (int nt = 0; nt < 4; ++nt) {
    short4 o4 = {f2bf(ot[nt][0] * inv), f2bf(ot[nt][1] * inv),
                 f2bf(ot[nt][2] * inv), f2bf(ot[nt][3] * inv)};
    *(short4*)(Ao + row + nt * 16 + quad * 4) = o4;
  }
}

extern "C" void kernel_launch(void* const* d_in, const int* in_sizes, int n_in,
                              void* d_out, int out_size, void* d_ws, size_t ws_size,
                              hipStream_t stream) {
  const float* q = (const float*)d_in[0];
  const float* k = (const float*)d_in[1];
  const float* v = (const float*)d_in[2];
  const int* mk = (const int*)d_in[3];
  const float* Wq = (const float*)d_in[4];
  const float* bq = (const float*)d_in[5];
  const float* Wk = (const float*)d_in[6];
  const float* bk = (const float*)d_in[7];
  const float* Wv = (const float*)d_in[8];
  const float* bv = (const float*)d_in[9];
  const float* Wo = (const float*)d_in[10];
  const float* bo = (const float*)d_in[11];

  const size_t XE = (size_t)M_ROWS * DM;  // 4194304
  const size_t WE = (size_t)DM * DM;      // 1048576
  short* xb = (short*)d_ws;               // 3*XE (dead after QKV gemm)
  short* Wt = xb + 3 * XE;                // 4*WE
  short* Qh = Wt + 4 * WE;                // 3*XE: Qh, Kh, Vt contiguous
  short* Ao = xb;                         // alias: xb region reused for Ao

  prep_x<<<dim3(1024, 1, 3), 256, 0, stream>>>(q, k, v, xb);
  prep_w<<<dim3(16, 16, 4), 256, 0, stream>>>(Wq, Wk, Wv, Wo, Wt);
  gemm_bt<0><<<dim3(M_ROWS / 128, DM / 128, 3), 256, 0, stream>>>(
      xb, Wt, bq, bk, bv, Qh, nullptr);
  attn_kernel<<<dim3(T_SEQ / 64, NB * NH), 256, 0, stream>>>(
      Qh, Qh + XE, Qh + 2 * XE, mk, Ao);
  gemm_bt<1><<<dim3(M_ROWS / 128, DM / 128, 1), 256, 0, stream>>>(
      Ao, Wt + 3 * WE, bo, nullptr, nullptr, nullptr, (float*)d_out);
}